// Round 8
// baseline (179.789 us; speedup 1.0000x reference)
//
#include <hip/hip_runtime.h>
#include <hip/hip_bf16.h>
#include <stdint.h>

#define BS   16384
#define NC   2000
#define NCP  2048            // padded N (wn zero-filled rows 2000..2047)
#define EMB  512
#define NAUX 5
#define NCHUNK 32            // partial chunks per row: nTile*2 + wvN

typedef __bf16 bf16x8 __attribute__((ext_vector_type(8)));
typedef float  f32x4  __attribute__((ext_vector_type(4)));

// ---------------------------------------------------------------------------
// Kernel 1: row-normalize features (rows [0,BS)) and word_embed ([BS,BS+NC))
// into bf16; zero-fill wn padding rows [NC,NCP). 16 lanes per row.
// ---------------------------------------------------------------------------
__global__ __launch_bounds__(256) void norm_kernel(
    const float* __restrict__ feat, const float* __restrict__ wemb,
    __bf16* __restrict__ fn, __bf16* __restrict__ wn)
{
    const int sub = threadIdx.x & 15;                    // lane-in-row
    const int row = blockIdx.x * 16 + (threadIdx.x >> 4);

    if (row >= BS + NC) {  // padding rows of wn -> zeros (masked in epilogue)
        bf16x8 z = {};
        bf16x8* d = (bf16x8*)(wn + (size_t)(row - BS) * EMB) + sub * 4;
        #pragma unroll
        for (int i = 0; i < 4; ++i) d[i] = z;
        return;
    }
    const float* src;
    __bf16* dst;
    if (row < BS) { src = feat + (size_t)row * EMB;        dst = fn + (size_t)row * EMB; }
    else          { src = wemb + (size_t)(row - BS) * EMB; dst = wn + (size_t)(row - BS) * EMB; }

    const float4* s4 = (const float4*)src + sub * 8;     // 32 floats per lane
    float4 x[8];
    float ss = 0.f;
    #pragma unroll
    for (int i = 0; i < 8; ++i) {
        x[i] = s4[i];
        ss += x[i].x * x[i].x + x[i].y * x[i].y + x[i].z * x[i].z + x[i].w * x[i].w;
    }
    #pragma unroll
    for (int m = 1; m < 16; m <<= 1) ss += __shfl_xor(ss, m, 64);
    const float scale = 1.0f / fmaxf(sqrtf(ss), 1e-12f);

    bf16x8* d = (bf16x8*)dst + sub * 4;
    #pragma unroll
    for (int i = 0; i < 4; ++i) {
        bf16x8 o;
        o[0] = (__bf16)(x[2*i].x   * scale); o[1] = (__bf16)(x[2*i].y   * scale);
        o[2] = (__bf16)(x[2*i].z   * scale); o[3] = (__bf16)(x[2*i].w   * scale);
        o[4] = (__bf16)(x[2*i+1].x * scale); o[5] = (__bf16)(x[2*i+1].y * scale);
        o[6] = (__bf16)(x[2*i+1].z * scale); o[7] = (__bf16)(x[2*i+1].w * scale);
        d[i] = o;
    }
}

// ---------------------------------------------------------------------------
// Kernel 2: XCD-swizzled m97 GEMM + FULLY fused epilogue:
//   es  partial: sum exp2((v-1)*20*log2e)
//   ta  partial: v * (19*[col==label] + 0.2*sum_j [col==aux_j])
//                (loss_i = 20 + log(es_tot) - ta_tot)
//   key partial: packed argmax (value bits | 2047-col)
// Labels/aux for the block's 128 rows staged in LDS (3 KB) at kernel start.
// Partials written [row][NCHUNK] so the finalize reads coalesced.
// mfma_f32_16x16x32_bf16 verified layouts:
//   A frag: lane(m=lane&15, q=lane>>4) holds A[m][q*8+j]
//   B frag: lane(n=lane&15, q)         holds B[q*8+j][n] = wn[n][q*8+j]
//   C/D:    col(n) = lane&15, row(m) = q*4 + reg
// ---------------------------------------------------------------------------
__global__ __launch_bounds__(256) void main_kernel(
    const __bf16* __restrict__ fn, const __bf16* __restrict__ wn,
    const int* __restrict__ label, const int* __restrict__ aux,
    float* __restrict__ es_p, float* __restrict__ ta_p,
    unsigned* __restrict__ key_p)
{
    __shared__ __align__(16) __bf16 As[128 * 64];
    __shared__ __align__(16) __bf16 Bs[128 * 64];
    __shared__ int lab_s[128];
    __shared__ int aux_s[128 * NAUX];

    const int tid   = threadIdx.x;
    const int lane  = tid & 63;
    const int l15   = lane & 15;
    const int quad  = lane >> 4;
    const int wv    = tid >> 6;
    const int wvM   = wv >> 1;
    const int wvN   = wv & 1;
    // XCD swizzle: xcd = bid&7 -> mTiles [xcd*16, xcd*16+16), mTile-major.
    const int xcd   = blockIdx.x & 7;
    const int j     = blockIdx.x >> 3;           // 0..255 within XCD
    const int mTile = xcd * 16 + (j >> 4);       // 0..127
    const int nTile = j & 15;                    // 0..15
    const int mBase = mTile * 128;

    if (tid < 128) lab_s[tid] = label[mBase + tid];
    for (int i = tid; i < 128 * NAUX; i += 256) aux_s[i] = aux[(size_t)mBase * NAUX + i];

    const __bf16* fbase = fn + (size_t)mBase * EMB;
    const __bf16* wbase = wn + (size_t)nTile * 128 * EMB;

    // Per-lane staging geometry: slot = wv*4+p covers LDS rows slot*8..+8.
    const int sRowIn = lane >> 3;                 // 0..7
    const int sChunk = (lane & 7) ^ sRowIn;       // logical 16B chunk to fetch
    f32x4 acc[4][4] = {};

    for (int kk = 0; kk < EMB; kk += 64) {
        __syncthreads();                          // previous tile's readers done
        #pragma unroll
        for (int p = 0; p < 4; ++p) {
            const int slot = wv * 4 + p;
            const size_t goff = (size_t)(slot * 8 + sRowIn) * EMB + kk + sChunk * 8;
            __builtin_amdgcn_global_load_lds(
                (const __attribute__((address_space(1))) void*)(fbase + goff),
                (__attribute__((address_space(3))) void*)(As + slot * 512), 16, 0, 0);
            __builtin_amdgcn_global_load_lds(
                (const __attribute__((address_space(1))) void*)(wbase + goff),
                (__attribute__((address_space(3))) void*)(Bs + slot * 512), 16, 0, 0);
        }
        __builtin_amdgcn_s_waitcnt(0);            // drain global->LDS DMA
        __syncthreads();                          // staged tile visible to all

        #pragma unroll
        for (int kc = 0; kc < 2; ++kc) {
            bf16x8 aF[4], bF[4];
            #pragma unroll
            for (int i = 0; i < 4; ++i) {
                const int ar = wvM * 64 + i * 16 + l15;
                const int br = wvN * 64 + i * 16 + l15;
                const int ca = ((kc * 4 + quad) ^ (ar & 7)) * 8;
                const int cb = ((kc * 4 + quad) ^ (br & 7)) * 8;
                aF[i] = *(const bf16x8*)(As + ar * 64 + ca);
                bF[i] = *(const bf16x8*)(Bs + br * 64 + cb);
            }
            #pragma unroll
            for (int mi = 0; mi < 4; ++mi)
                #pragma unroll
                for (int ni = 0; ni < 4; ++ni)
                    acc[mi][ni] = __builtin_amdgcn_mfma_f32_16x16x32_bf16(
                        aF[mi], bF[ni], acc[mi][ni], 0, 0, 0);
        }
    }

    // ---- Fused epilogue ----
    const float C20 = 28.853900817779268f;  // 20*log2(e)
    const int chunk   = nTile * 2 + wvN;
    const int colBase = nTile * 128 + wvN * 64;
    #pragma unroll
    for (int mi = 0; mi < 4; ++mi) {
        float    es[4] = {0.f, 0.f, 0.f, 0.f};
        float    ta[4] = {0.f, 0.f, 0.f, 0.f};
        unsigned km[4] = {0u, 0u, 0u, 0u};
        #pragma unroll
        for (int r = 0; r < 4; ++r) {
            const int rl  = wvM * 64 + mi * 16 + quad * 4 + r;
            const int lab = lab_s[rl];
            int ax[NAUX];
            #pragma unroll
            for (int q = 0; q < NAUX; ++q) ax[q] = aux_s[rl * NAUX + q];
            #pragma unroll
            for (int ni = 0; ni < 4; ++ni) {
                const int col = colBase + ni * 16 + l15;
                const float v = acc[mi][ni][r];
                const float ve = (col < NC) ? v : -3.0f;   // mask padding
                es[r] += exp2f((ve - 1.0f) * C20);
                float w = (col == lab) ? 19.0f : 0.0f;     // 0.95*20
                #pragma unroll
                for (int q = 0; q < NAUX; ++q) w += (col == ax[q]) ? 0.2f : 0.0f;  // 0.01*20
                ta[r] += v * w;
                unsigned u = __float_as_uint(ve);
                unsigned k = u ^ (unsigned)(((int)u >> 31) | 0x80000000);
                unsigned pk = (k & 0xFFFFF800u) | (2047u - (unsigned)col);
                km[r] = pk > km[r] ? pk : km[r];
            }
        }
        #pragma unroll
        for (int r = 0; r < 4; ++r) {
            #pragma unroll
            for (int m = 1; m < 16; m <<= 1) {
                es[r] += __shfl_xor(es[r], m, 64);
                ta[r] += __shfl_xor(ta[r], m, 64);
                unsigned x = __shfl_xor(km[r], m, 64);
                km[r] = x > km[r] ? x : km[r];
            }
        }
        if (l15 == 0) {
            #pragma unroll
            for (int r = 0; r < 4; ++r) {
                const int row = mBase + wvM * 64 + mi * 16 + quad * 4 + r;
                es_p [(size_t)row * NCHUNK + chunk] = es[r];
                ta_p [(size_t)row * NCHUNK + chunk] = ta[r];
                key_p[(size_t)row * NCHUNK + chunk] = km[r];
            }
        }
    }
}

// ---------------------------------------------------------------------------
// Kernel 3: finalize. [row][32] partials, 32 lanes per row (coalesced),
// 5-round shfl combine, per-block partial, one atomicAdd pair per block.
// ---------------------------------------------------------------------------
__global__ __launch_bounds__(256) void fin_kernel(
    const float* __restrict__ es_p, const float* __restrict__ ta_p,
    const unsigned* __restrict__ key_p, const int* __restrict__ label,
    float* __restrict__ out)
{
    const int lane = threadIdx.x & 63;
    const int wv   = threadIdx.x >> 6;
    const int c    = lane & 31;
    const int sub  = lane >> 5;          // 0/1: which row of the pair

    float lsum = 0.f, asum = 0.f;
    for (int row = blockIdx.x * 8 + wv * 2 + sub; row < BS; row += 256 * 8) {
        float    es = es_p [(size_t)row * NCHUNK + c];
        float    ta = ta_p [(size_t)row * NCHUNK + c];
        unsigned k  = key_p[(size_t)row * NCHUNK + c];
        #pragma unroll
        for (int m = 1; m < 32; m <<= 1) {
            es += __shfl_xor(es, m, 64);
            ta += __shfl_xor(ta, m, 64);
            unsigned x = __shfl_xor(k, m, 64);
            k = x > k ? x : k;
        }
        if (c == 0) {
            const int amax = 2047 - (int)(k & 0x7FFu);
            lsum += 20.0f + logf(es) - ta;
            asum += (amax == label[row]) ? 1.0f : 0.0f;
        }
    }
    #pragma unroll
    for (int m = 1; m < 64; m <<= 1) {
        lsum += __shfl_xor(lsum, m, 64);
        asum += __shfl_xor(asum, m, 64);
    }
    __shared__ float sl[4], sa[4];
    if (lane == 0) { sl[wv] = lsum; sa[wv] = asum; }
    __syncthreads();
    if (threadIdx.x == 0) {
        atomicAdd(&out[0], (sl[0] + sl[1] + sl[2] + sl[3]) / (float)BS);
        atomicAdd(&out[1], (sa[0] + sa[1] + sa[2] + sa[3]) / (float)BS);
    }
}

// ---------------------------------------------------------------------------
// Workspace layout (bytes):
//   fn    @ 0         (16,777,216)  BS x 512 bf16
//   wn    @ 16777216  ( 2,097,152)  NCP(2048) x 512 bf16 (rows >=2000 zero)
//   es_p  @ 18874368  ( 2,097,152)  [BS][32] f32
//   ta_p  @ 20971520  ( 2,097,152)  [BS][32] f32
//   key_p @ 23068672  ( 2,097,152)  [BS][32] u32
// ---------------------------------------------------------------------------
extern "C" void kernel_launch(void* const* d_in, const int* in_sizes, int n_in,
                              void* d_out, int out_size, void* d_ws, size_t ws_size,
                              hipStream_t stream)
{
    const float* feat  = (const float*)d_in[0];
    const float* wemb  = (const float*)d_in[1];
    const int*   label = (const int*)d_in[2];
    const int*   aux   = (const int*)d_in[3];

    char* ws = (char*)d_ws;
    __bf16*   fn    = (__bf16*)(ws);
    __bf16*   wn    = (__bf16*)(ws + 16777216);
    float*    es_p  = (float*)(ws + 18874368);
    float*    ta_p  = (float*)(ws + 20971520);
    unsigned* key_p = (unsigned*)(ws + 23068672);
    float*    out   = (float*)d_out;

    hipMemsetAsync(out, 0, 2 * sizeof(float), stream);  // atomics accumulate into zeroed out
    hipLaunchKernelGGL(norm_kernel, dim3((BS + NCP) / 16), dim3(256), 0, stream,
                       feat, wemb, fn, wn);
    hipLaunchKernelGGL(main_kernel, dim3((BS / 128) * (NCP / 128)), dim3(256), 0, stream,
                       fn, wn, label, aux, es_p, ta_p, key_p);
    hipLaunchKernelGGL(fin_kernel, dim3(256), dim3(256), 0, stream,
                       es_p, ta_p, key_p, label, out);
}